// Round 1
// baseline (2757.500 us; speedup 1.0000x reference)
//
#include <hip/hip_runtime.h>

#define BATCH 4096

// ---------------- conv1: x[B,3,48,64] * w[32,3,8,8] s4 -> y[B,32,11,15] (pre-ReLU stored) ----------------
__global__ __launch_bounds__(256) void conv1_kernel(const float* __restrict__ x,
                                                    const float* __restrict__ w,
                                                    const float* __restrict__ bias,
                                                    float* __restrict__ y) {
    int idx = blockIdx.x * 256 + threadIdx.x;
    const int total = BATCH * 32 * 11 * 15;
    if (idx >= total) return;
    int ow = idx % 15;
    int t  = idx / 15;
    int oh = t % 11; t /= 11;
    int oc = t % 32;
    int b  = t / 32;

    const float* xb = x + (size_t)b * (3 * 48 * 64);
    const float* wo = w + oc * (3 * 8 * 8);
    float acc = bias[oc];
    for (int ic = 0; ic < 3; ++ic) {
        const float* xc = xb + ic * (48 * 64) + (oh * 4) * 64 + ow * 4;
        const float* wc = wo + ic * 64;
        #pragma unroll
        for (int kh = 0; kh < 8; ++kh) {
            #pragma unroll
            for (int kw = 0; kw < 8; ++kw) {
                acc += xc[kh * 64 + kw] * wc[kh * 8 + kw];
            }
        }
    }
    y[idx] = acc;
}

// ---------------- conv2: relu(x1)[B,32,11,15] * w[64,32,3,3] s2 -> y[B,64,5,7] ----------------
__global__ __launch_bounds__(256) void conv2_kernel(const float* __restrict__ x1,
                                                    const float* __restrict__ w,
                                                    const float* __restrict__ bias,
                                                    float* __restrict__ y) {
    int idx = blockIdx.x * 256 + threadIdx.x;
    const int total = BATCH * 64 * 5 * 7;
    if (idx >= total) return;
    int ow = idx % 7;
    int t  = idx / 7;
    int oh = t % 5; t /= 5;
    int oc = t % 64;
    int b  = t / 64;

    const float* xb = x1 + (size_t)b * (32 * 165);
    const float* wo = w + oc * (32 * 9);
    float acc = bias[oc];
    for (int ic = 0; ic < 32; ++ic) {
        const float* xc = xb + ic * 165 + (oh * 2) * 15 + ow * 2;
        const float* wc = wo + ic * 9;
        #pragma unroll
        for (int kh = 0; kh < 3; ++kh) {
            #pragma unroll
            for (int kw = 0; kw < 3; ++kw) {
                float v = xc[kh * 15 + kw];
                v = v > 0.f ? v : 0.f;
                acc += v * wc[kh * 3 + kw];
            }
        }
    }
    y[idx] = acc;
}

// ---------------- conv3: relu(x3)[B,64,5,7] * w[64,64,3,3] s1 -> y[B,64,3,5] ----------------
__global__ __launch_bounds__(256) void conv3_kernel(const float* __restrict__ x3,
                                                    const float* __restrict__ w,
                                                    const float* __restrict__ bias,
                                                    float* __restrict__ y) {
    int idx = blockIdx.x * 256 + threadIdx.x;
    const int total = BATCH * 64 * 3 * 5;
    if (idx >= total) return;
    int ow = idx % 5;
    int t  = idx / 5;
    int oh = t % 3; t /= 3;
    int oc = t % 64;
    int b  = t / 64;

    const float* xb = x3 + (size_t)b * (64 * 35);
    const float* wo = w + oc * (64 * 9);
    float acc = bias[oc];
    for (int ic = 0; ic < 64; ++ic) {
        const float* xc = xb + ic * 35 + oh * 7 + ow;
        const float* wc = wo + ic * 9;
        #pragma unroll
        for (int kh = 0; kh < 3; ++kh) {
            #pragma unroll
            for (int kw = 0; kw < 3; ++kw) {
                float v = xc[kh * 7 + kw];
                v = v > 0.f ? v : 0.f;
                acc += v * wc[kh * 3 + kw];
            }
        }
    }
    y[idx] = acc;
}

// ---------------- fc4: h = relu(relu(x5)[B,960] @ w4^T[960,512] + b4) ----------------
// block = 512 threads (one per oc), handles 8 batches; x5 rows staged in LDS.
__global__ __launch_bounds__(512) void fc4_kernel(const float* __restrict__ x5,
                                                  const float* __restrict__ w4,
                                                  const float* __restrict__ b4,
                                                  float* __restrict__ h) {
    __shared__ float xs[8][960];
    int b0 = blockIdx.x * 8;
    for (int i = threadIdx.x; i < 8 * 960; i += 512) {
        float v = x5[(size_t)b0 * 960 + i];
        xs[i / 960][i % 960] = v > 0.f ? v : 0.f;
    }
    __syncthreads();

    int oc = threadIdx.x;
    const float* wrow = w4 + (size_t)oc * 960;
    float acc[8];
    float bb = b4[oc];
    #pragma unroll
    for (int j = 0; j < 8; ++j) acc[j] = bb;
    for (int k = 0; k < 960; ++k) {
        float wv = wrow[k];
        #pragma unroll
        for (int j = 0; j < 8; ++j) acc[j] += wv * xs[j][k];
    }
    #pragma unroll
    for (int j = 0; j < 8; ++j) {
        float v = acc[j];
        h[(size_t)(b0 + j) * 512 + oc] = v > 0.f ? v : 0.f;
    }
}

// ---------------- fc5: out = h[B,512] @ w5^T[512,2] + b5 ----------------
__global__ __launch_bounds__(256) void fc5_kernel(const float* __restrict__ h,
                                                  const float* __restrict__ w5,
                                                  const float* __restrict__ b5,
                                                  float* __restrict__ out) {
    int idx = blockIdx.x * 256 + threadIdx.x;
    if (idx >= BATCH * 2) return;
    int oc = idx & 1;
    int b  = idx >> 1;
    const float* hr = h + (size_t)b * 512;
    const float* wr = w5 + oc * 512;
    float acc = b5[oc];
    for (int k = 0; k < 512; ++k) acc += hr[k] * wr[k];
    out[idx] = acc;
}

// ---------------- spatial reduction: sum over (b,c) slabs of HW-contiguous maps ----------------
// dst[pos] += scale * sum_{slab} src[slab*HW + pos]
template <int HW>
__global__ __launch_bounds__(256) void reduce_hw_kernel(const float* __restrict__ src,
                                                        int BC, float scale,
                                                        float* __restrict__ dst) {
    constexpr int G = 256 / HW;   // thread groups per block
    __shared__ float s[HW];
    int t = threadIdx.x;
    if (t < HW) s[t] = 0.f;
    __syncthreads();
    int g   = t / HW;
    int pos = t - g * HW;
    if (g < G) {
        float acc = 0.f;
        int stride = gridDim.x * G;
        for (int slab = blockIdx.x * G + g; slab < BC; slab += stride) {
            acc += src[(size_t)slab * HW + pos];
        }
        atomicAdd(&s[pos], acc);
    }
    __syncthreads();
    if (t < HW) atomicAdd(&dst[t], s[t] * scale);
}

// zero the ave region of d_out (harness re-poisons d_out to 0xAA before timed launches)
__global__ void zero_tail_kernel(float* __restrict__ out) {
    int t = threadIdx.x;
    if (t < 215) out[8192 + t] = 0.f;
}

extern "C" void kernel_launch(void* const* d_in, const int* in_sizes, int n_in,
                              void* d_out, int out_size, void* d_ws, size_t ws_size,
                              hipStream_t stream) {
    const float* x  = (const float*)d_in[0];
    const float* w1 = (const float*)d_in[1];
    const float* b1 = (const float*)d_in[2];
    const float* w2 = (const float*)d_in[3];
    const float* b2 = (const float*)d_in[4];
    const float* w3 = (const float*)d_in[5];
    const float* b3 = (const float*)d_in[6];
    const float* w4 = (const float*)d_in[7];
    const float* b4 = (const float*)d_in[8];
    const float* w5 = (const float*)d_in[9];
    const float* b5 = (const float*)d_in[10];
    float* out = (float*)d_out;

    float* ws = (float*)d_ws;
    const size_t X1_OFF = 0;                      // 4096*32*165 = 21,626,880
    const size_t X3_OFF = X1_OFF + 21626880;      //  9,175,040
    const size_t X5_OFF = X3_OFF + 9175040;       //  3,932,160
    const size_t H_OFF  = X5_OFF + 3932160;       //  2,097,152
    float* x1 = ws + X1_OFF;
    float* x3 = ws + X3_OFF;
    float* x5 = ws + X5_OFF;
    float* h  = ws + H_OFF;

    zero_tail_kernel<<<1, 256, 0, stream>>>(out);

    conv1_kernel<<<(BATCH * 32 * 11 * 15) / 256, 256, 0, stream>>>(x, w1, b1, x1);
    reduce_hw_kernel<165><<<1024, 256, 0, stream>>>(x1, BATCH * 32, 1.0f / 32.0f, out + 8192);

    conv2_kernel<<<(BATCH * 64 * 5 * 7) / 256, 256, 0, stream>>>(x1, w2, b2, x3);
    reduce_hw_kernel<35><<<1024, 256, 0, stream>>>(x3, BATCH * 64, 1.0f / 64.0f, out + 8192 + 165);

    conv3_kernel<<<(BATCH * 64 * 3 * 5) / 256, 256, 0, stream>>>(x3, w3, b3, x5);
    reduce_hw_kernel<15><<<1024, 256, 0, stream>>>(x5, BATCH * 64, 1.0f / 64.0f, out + 8192 + 200);

    fc4_kernel<<<BATCH / 8, 512, 0, stream>>>(x5, w4, b4, h);
    fc5_kernel<<<(BATCH * 2 + 255) / 256, 256, 0, stream>>>(h, w5, b5, out);
}

// Round 2
// 906.953 us; speedup vs baseline: 3.0404x; 3.0404x over previous
//
#include <hip/hip_runtime.h>

#define BATCH 4096

__device__ __forceinline__ float frelu(float v) { return v > 0.f ? v : 0.f; }

// ---------------- init d_out: logits pre-loaded with b5 (fc5 accumulates via atomics), ave tail zeroed ----------------
__global__ void init_out_kernel(float* __restrict__ out, const float* __restrict__ b5) {
    int i = blockIdx.x * 256 + threadIdx.x;
    if (i < 8192)       out[i] = b5[i & 1];
    else if (i < 8407)  out[i] = 0.f;
}

// ---------------- conv1: x[B,3,48,64] * w[32,3,8,8] s4 -> y[B,32,11,15] pre-ReLU; fused ave1 ----------------
// One block per image. Whole image (36 KB) staged in LDS. 384 threads: wave-uniform
// och = tid/192 (0/1) so weight addresses are scalar (s_load); 16 accumulators/thread.
__global__ __launch_bounds__(384) void conv1_kernel(const float* __restrict__ x,
                                                    const float* __restrict__ w,
                                                    const float* __restrict__ bias,
                                                    float* __restrict__ y,
                                                    float* __restrict__ ave) {
    __shared__ float xs[9216];
    __shared__ float red[165];
    const int img = blockIdx.x;
    const int tid = threadIdx.x;

    const float4* xg = (const float4*)(x + (size_t)img * 9216);
    float4* xs4 = (float4*)xs;
    for (int i = tid; i < 2304; i += 384) xs4[i] = xg[i];
    if (tid < 165) red[tid] = 0.f;
    __syncthreads();

    const int och = __builtin_amdgcn_readfirstlane(tid / 192);  // wave-uniform (192 = 3 waves)
    const int p   = tid % 192;
    const bool active = (p < 165);
    const int pp = active ? p : 0;
    const int oh = pp / 15, ow = pp % 15;

    float acc[16];
    const float* wb = w + och * (16 * 192);
    #pragma unroll
    for (int o = 0; o < 16; ++o) acc[o] = bias[och * 16 + o];

    for (int ic = 0; ic < 3; ++ic) {
        const float* xr0 = xs + ic * 3072 + oh * 256 + ow * 4;
        for (int kh = 0; kh < 8; ++kh) {
            const float4 a = *(const float4*)(xr0 + kh * 64);
            const float4 b = *(const float4*)(xr0 + kh * 64 + 4);
            const float* wr = wb + ic * 64 + kh * 8;
            #pragma unroll
            for (int o = 0; o < 16; ++o) {
                const float* wo = wr + o * 192;
                acc[o] += a.x * wo[0] + a.y * wo[1] + a.z * wo[2] + a.w * wo[3]
                        + b.x * wo[4] + b.y * wo[5] + b.z * wo[6] + b.w * wo[7];
            }
        }
    }

    if (active) {
        float s = 0.f;
        size_t yb = ((size_t)img * 32 + och * 16) * 165 + p;
        #pragma unroll
        for (int o = 0; o < 16; ++o) { y[yb + (size_t)o * 165] = acc[o]; s += acc[o]; }
        atomicAdd(&red[p], s);
    }
    __syncthreads();
    if (tid < 165) atomicAdd(&ave[tid], red[tid] * 0.03125f);  // /32
}

// ---------------- conv2: relu(x1)[B,32,11,15] * w[64,32,3,3] s2 -> y[B,64,5,7] pre-ReLU; fused ave2 ----------------
// thread = (b,pos), 32 ocs per thread (oc half selected by blockIdx.y -> uniform weight addrs).
__global__ __launch_bounds__(256) void conv2_kernel(const float* __restrict__ x1,
                                                    const float* __restrict__ w,
                                                    const float* __restrict__ bias,
                                                    float* __restrict__ y,
                                                    float* __restrict__ ave) {
    __shared__ float red[35];
    const int tid = threadIdx.x;
    if (tid < 35) red[tid] = 0.f;
    __syncthreads();

    const int tg  = blockIdx.x * 256 + tid;            // grid.x = 560 exactly
    const int b   = tg / 35;
    const int pos = tg - b * 35;
    const int oh  = pos / 7, ow = pos - (pos / 7) * 7;
    const int oc0 = blockIdx.y * 32;

    float acc[32];
    #pragma unroll
    for (int o = 0; o < 32; ++o) acc[o] = bias[oc0 + o];
    const float* wb = w + (size_t)oc0 * 288;           // w2[oc][ic][3][3]

    for (int ic = 0; ic < 32; ++ic) {
        const float* xc = x1 + ((size_t)b * 32 + ic) * 165;
        #pragma unroll
        for (int kh = 0; kh < 3; ++kh) {
            const float* xr = xc + (oh * 2 + kh) * 15 + ow * 2;
            float x0 = frelu(xr[0]), x1v = frelu(xr[1]), x2v = frelu(xr[2]);
            const float* wr = wb + ic * 9 + kh * 3;
            #pragma unroll
            for (int o = 0; o < 32; ++o) {
                const float* wo = wr + o * 288;
                acc[o] += x0 * wo[0] + x1v * wo[1] + x2v * wo[2];
            }
        }
    }

    float s = 0.f;
    size_t yb = ((size_t)b * 64 + oc0) * 35 + pos;
    #pragma unroll
    for (int o = 0; o < 32; ++o) { y[yb + (size_t)o * 35] = acc[o]; s += acc[o]; }
    atomicAdd(&red[pos], s);
    __syncthreads();
    if (tid < 35) atomicAdd(&ave[tid], red[tid] * 0.015625f);  // /64
}

// ---------------- conv3: relu(x3)[B,64,5,7] * w[64,64,3,3] s1 -> y[B,64,3,5] pre-ReLU; fused ave3 ----------------
// thread = (b,pos), 16 ocs per thread (quarter by blockIdx.y).
__global__ __launch_bounds__(256) void conv3_kernel(const float* __restrict__ x3,
                                                    const float* __restrict__ w,
                                                    const float* __restrict__ bias,
                                                    float* __restrict__ y,
                                                    float* __restrict__ ave) {
    __shared__ float red[15];
    const int tid = threadIdx.x;
    if (tid < 15) red[tid] = 0.f;
    __syncthreads();

    const int tg  = blockIdx.x * 256 + tid;            // grid.x = 240 exactly
    const int b   = tg / 15;
    const int pos = tg - b * 15;
    const int oh  = pos / 5, ow = pos - (pos / 5) * 5;
    const int oc0 = blockIdx.y * 16;

    float acc[16];
    #pragma unroll
    for (int o = 0; o < 16; ++o) acc[o] = bias[oc0 + o];
    const float* wb = w + (size_t)oc0 * 576;           // w3[oc][ic][3][3]

    for (int ic = 0; ic < 64; ++ic) {
        const float* xc = x3 + ((size_t)b * 64 + ic) * 35;
        #pragma unroll
        for (int kh = 0; kh < 3; ++kh) {
            const float* xr = xc + (oh + kh) * 7 + ow;
            float x0 = frelu(xr[0]), x1v = frelu(xr[1]), x2v = frelu(xr[2]);
            const float* wr = wb + ic * 9 + kh * 3;
            #pragma unroll
            for (int o = 0; o < 16; ++o) {
                const float* wo = wr + o * 576;
                acc[o] += x0 * wo[0] + x1v * wo[1] + x2v * wo[2];
            }
        }
    }

    float s = 0.f;
    size_t yb = ((size_t)b * 64 + oc0) * 15 + pos;
    #pragma unroll
    for (int o = 0; o < 16; ++o) { y[yb + (size_t)o * 15] = acc[o]; s += acc[o]; }
    atomicAdd(&red[pos], s);
    __syncthreads();
    if (tid < 15) atomicAdd(&ave[tid], red[tid] * 0.015625f);  // /64
}

// ---------------- fc4+fc5 fused: out[b,2] += relu(relu(x5)@w4^T + b4) @ w5^T ----------------
// Tiled GEMM BM=64 (batch) x BN=32 (oc) x BK=32, block=128, 4x4 register tile.
// h is never materialized; logits accumulate via atomics (out pre-loaded with b5).
__global__ __launch_bounds__(128) void fc4_kernel(const float* __restrict__ x5,
                                                  const float* __restrict__ w4,
                                                  const float* __restrict__ b4,
                                                  const float* __restrict__ w5,
                                                  float* __restrict__ out) {
    __shared__ float As[64][36];
    __shared__ float Bs[32][36];
    __shared__ float lred[64][2];
    const int tid = threadIdx.x;
    const int m0 = blockIdx.x * 64;
    const int n0 = blockIdx.y * 32;

    lred[tid >> 1][tid & 1] = 0.f;

    float acc[4][4] = {};
    const int tm = tid & 15, tn = tid >> 4;     // tm:16 x tn:8
    const int alm = tid >> 1, ahalf = tid & 1;  // A stage: row, k-half(16)
    const int blm = tid >> 2, bq = tid & 3;     // B stage: row, k-eighth(8)

    for (int k0 = 0; k0 < 960; k0 += 32) {
        __syncthreads();
        const float4* ag = (const float4*)(x5 + (size_t)(m0 + alm) * 960 + k0 + ahalf * 16);
        float4 av0 = ag[0], av1 = ag[1], av2 = ag[2], av3 = ag[3];
        av0.x = frelu(av0.x); av0.y = frelu(av0.y); av0.z = frelu(av0.z); av0.w = frelu(av0.w);
        av1.x = frelu(av1.x); av1.y = frelu(av1.y); av1.z = frelu(av1.z); av1.w = frelu(av1.w);
        av2.x = frelu(av2.x); av2.y = frelu(av2.y); av2.z = frelu(av2.z); av2.w = frelu(av2.w);
        av3.x = frelu(av3.x); av3.y = frelu(av3.y); av3.z = frelu(av3.z); av3.w = frelu(av3.w);
        float4* ad = (float4*)&As[alm][ahalf * 16];
        ad[0] = av0; ad[1] = av1; ad[2] = av2; ad[3] = av3;

        const float4* bg = (const float4*)(w4 + (size_t)(n0 + blm) * 960 + k0 + bq * 8);
        float4 bv0 = bg[0], bv1 = bg[1];
        float4* bd = (float4*)&Bs[blm][bq * 8];
        bd[0] = bv0; bd[1] = bv1;
        __syncthreads();

        #pragma unroll
        for (int k4 = 0; k4 < 8; ++k4) {
            float4 afr[4], bfr[4];
            #pragma unroll
            for (int j = 0; j < 4; ++j) afr[j] = *(const float4*)&As[tm * 4 + j][k4 * 4];
            #pragma unroll
            for (int j = 0; j < 4; ++j) bfr[j] = *(const float4*)&Bs[tn * 4 + j][k4 * 4];
            #pragma unroll
            for (int i = 0; i < 4; ++i)
                #pragma unroll
                for (int j = 0; j < 4; ++j)
                    acc[i][j] += afr[i].x * bfr[j].x + afr[i].y * bfr[j].y
                               + afr[i].z * bfr[j].z + afr[i].w * bfr[j].w;
        }
    }

    // epilogue: bias + relu + fc5 partial
    float w5v[2][4];
    #pragma unroll
    for (int o = 0; o < 2; ++o)
        #pragma unroll
        for (int j = 0; j < 4; ++j) w5v[o][j] = w5[o * 512 + n0 + tn * 4 + j];
    float b4v[4];
    #pragma unroll
    for (int j = 0; j < 4; ++j) b4v[j] = b4[n0 + tn * 4 + j];

    #pragma unroll
    for (int i = 0; i < 4; ++i) {
        float l0 = 0.f, l1 = 0.f;
        #pragma unroll
        for (int j = 0; j < 4; ++j) {
            float h = frelu(acc[i][j] + b4v[j]);
            l0 += h * w5v[0][j];
            l1 += h * w5v[1][j];
        }
        atomicAdd(&lred[tm * 4 + i][0], l0);
        atomicAdd(&lred[tm * 4 + i][1], l1);
    }
    __syncthreads();
    {
        int m = tid >> 1, o = tid & 1;
        atomicAdd(&out[(size_t)(m0 + m) * 2 + o], lred[m][o]);
    }
}

extern "C" void kernel_launch(void* const* d_in, const int* in_sizes, int n_in,
                              void* d_out, int out_size, void* d_ws, size_t ws_size,
                              hipStream_t stream) {
    const float* x  = (const float*)d_in[0];
    const float* w1 = (const float*)d_in[1];
    const float* b1 = (const float*)d_in[2];
    const float* w2 = (const float*)d_in[3];
    const float* b2 = (const float*)d_in[4];
    const float* w3 = (const float*)d_in[5];
    const float* b3 = (const float*)d_in[6];
    const float* w4 = (const float*)d_in[7];
    const float* b4 = (const float*)d_in[8];
    const float* w5 = (const float*)d_in[9];
    const float* b5 = (const float*)d_in[10];
    float* out = (float*)d_out;

    float* ws = (float*)d_ws;
    float* x1 = ws;                         // 4096*32*165 = 21,626,880 floats
    float* x3 = ws + 21626880;              // 4096*64*35  =  9,175,040
    float* x5 = ws + 30801920;              // 4096*64*15  =  3,932,160

    float* ave1 = out + 8192;
    float* ave2 = out + 8192 + 165;
    float* ave3 = out + 8192 + 200;

    init_out_kernel<<<33, 256, 0, stream>>>(out, b5);

    conv1_kernel<<<BATCH, 384, 0, stream>>>(x, w1, b1, x1, ave1);

    conv2_kernel<<<dim3(560, 2), 256, 0, stream>>>(x1, w2, b2, x3, ave2);

    conv3_kernel<<<dim3(240, 4), 256, 0, stream>>>(x3, w3, b3, x5, ave3);

    fc4_kernel<<<dim3(64, 16), 128, 0, stream>>>(x5, w4, b4, w5, out);
}

// Round 3
// 364.481 us; speedup vs baseline: 7.5656x; 2.4883x over previous
//
#include <hip/hip_runtime.h>
#include <hip/hip_bf16.h>

#define BATCH 4096

typedef __attribute__((ext_vector_type(8))) short short8;
typedef __attribute__((ext_vector_type(4))) float f32x4;

#define MFMA_BF16 __builtin_amdgcn_mfma_f32_16x16x32_bf16

__device__ __forceinline__ float frelu(float v) { return v > 0.f ? v : 0.f; }
__device__ __forceinline__ unsigned short f2bf(float f) {
    return __builtin_bit_cast(unsigned short, __float2bfloat16(f));
}
__device__ __forceinline__ short8 cvt8(const float* p) {
    float4 a = *(const float4*)p;
    float4 b = *(const float4*)(p + 4);
    short8 r;
    r[0] = (short)f2bf(a.x); r[1] = (short)f2bf(a.y); r[2] = (short)f2bf(a.z); r[3] = (short)f2bf(a.w);
    r[4] = (short)f2bf(b.x); r[5] = (short)f2bf(b.y); r[6] = (short)f2bf(b.z); r[7] = (short)f2bf(b.w);
    return r;
}

// ---------------- prep: permute+cvt weights to bf16 K-contiguous layouts; init out ----------------
// w2p[oc][khw*32+ic], w3p[oc][khw*64+ic], w4p[n][pos*64+oc]; out[0..8191]=b5; ave tail zero.
__global__ __launch_bounds__(256) void prep_kernel(const float* __restrict__ w2, const float* __restrict__ w3,
                                                   const float* __restrict__ w4, const float* __restrict__ b5,
                                                   unsigned short* __restrict__ w2p, unsigned short* __restrict__ w3p,
                                                   unsigned short* __restrict__ w4p, float* __restrict__ out) {
    int idx = blockIdx.x * 256 + threadIdx.x;
    if (idx < 18432) {
        int oc = idx / 288, k = idx % 288;
        int khw = k / 32, ic = k % 32;
        w2p[idx] = f2bf(w2[oc * 288 + ic * 9 + khw]);
    } else if (idx < 55296) {
        int j = idx - 18432;
        int oc = j / 576, k = j % 576;
        int khw = k / 64, ic = k % 64;
        w3p[j] = f2bf(w3[oc * 576 + ic * 9 + khw]);
    } else if (idx < 546816) {
        int j = idx - 55296;
        int n = j / 960, k = j % 960;
        int pos = k / 64, oc = k % 64;
        w4p[j] = f2bf(w4[n * 960 + oc * 15 + pos]);
    } else if (idx < 555008) {
        int j = idx - 546816;
        out[j] = b5[j & 1];
    } else if (idx < 555223) {
        out[8192 + (idx - 555008)] = 0.f;
    }
}

// ---------------- conv1 (MFMA): x[B,3,48,64]*w1[32,192] -> x2 bf16 NHWC [B,165,32]; red1 partials ----------------
__global__ __launch_bounds__(256) void conv1_mfma(const float* __restrict__ x,
                                                  const float* __restrict__ w1, const float* __restrict__ b1,
                                                  unsigned short* __restrict__ x2, float* __restrict__ red1) {
    __shared__ float red[176];
    const int img = blockIdx.x;
    const int tid = threadIdx.x;
    const int wave = tid >> 6, lane = tid & 63;
    const int col = lane & 15, quad = lane >> 4;
    if (tid < 176) red[tid] = 0.f;

    // weight fragments hoisted: 2 n-tiles x 6 k-chunks (k=(ic,kh,kw) natural order)
    short8 Bf[2][6];
    #pragma unroll
    for (int nt = 0; nt < 2; ++nt) {
        const int oc = nt * 16 + col;
        #pragma unroll
        for (int c = 0; c < 6; ++c)
            Bf[nt][c] = cvt8(w1 + oc * 192 + c * 32 + quad * 8);
    }
    const float bias0 = b1[col], bias1 = b1[col + 16];
    __syncthreads();

    const float* ximg = x + (size_t)img * 9216;
    #pragma unroll
    for (int ti = 0; ti < 3; ++ti) {
        const int t = wave + ti * 4;          // m-tile index, 11 tiles (165 pos, tile 10 partial)
        if (t >= 11) break;
        const int posA = t * 16 + col;        // A-row (m) for this lane
        const int pm = posA < 165 ? posA : 164;
        const int oh = pm / 15, ow = pm % 15;
        f32x4 acc0 = {0.f, 0.f, 0.f, 0.f}, acc1 = {0.f, 0.f, 0.f, 0.f};
        #pragma unroll
        for (int c = 0; c < 6; ++c) {
            const int ic = c >> 1;
            const int kh = (c & 1) * 4 + quad;
            const float* ap = ximg + (ic * 48 + oh * 4 + kh) * 64 + ow * 4;
            short8 af = cvt8(ap);
            acc0 = MFMA_BF16(af, Bf[0][c], acc0, 0, 0, 0);
            acc1 = MFMA_BF16(af, Bf[1][c], acc1, 0, 0, 0);
        }
        // C/D: col=lane&15 (oc), row = quad*4+r (pos)
        #pragma unroll
        for (int r = 0; r < 4; ++r) {
            const int pr = t * 16 + quad * 4 + r;
            float v0 = acc0[r] + bias0;
            float v1 = acc1[r] + bias1;
            float s = v0 + v1;
            s += __shfl_xor(s, 1); s += __shfl_xor(s, 2);
            s += __shfl_xor(s, 4); s += __shfl_xor(s, 8);
            if (pr < 165) {
                if (col == 0) atomicAdd(&red[pr], s);
                unsigned short* dst = x2 + ((size_t)img * 165 + pr) * 32;
                dst[col]      = f2bf(frelu(v0));
                dst[col + 16] = f2bf(frelu(v1));
            }
        }
    }
    __syncthreads();
    if (tid < 176) red1[(size_t)tid * 4096 + img] = red[tid];
}

// ---------------- reduce1: ave1[pos] = sum_img red1[pos][img] / 32 ----------------
__global__ __launch_bounds__(256) void reduce1_kernel(const float* __restrict__ red1, float* __restrict__ ave1) {
    const int pos = blockIdx.x;
    float s = 0.f;
    for (int i = threadIdx.x; i < 4096; i += 256) s += red1[(size_t)pos * 4096 + i];
    s += __shfl_down(s, 32); s += __shfl_down(s, 16); s += __shfl_down(s, 8);
    s += __shfl_down(s, 4);  s += __shfl_down(s, 2);  s += __shfl_down(s, 1);
    __shared__ float wsum[4];
    if ((threadIdx.x & 63) == 0) wsum[threadIdx.x >> 6] = s;
    __syncthreads();
    if (threadIdx.x == 0) ave1[pos] = (wsum[0] + wsum[1] + wsum[2] + wsum[3]) * 0.03125f;
}

// ---------------- conv2 (MFMA): x2[B,165,32] * w2p -> x4 bf16 NHWC [B,35,64]; fused ave2 ----------------
// M = 4096*35 = 143360 = 8960 tiles exactly. Block = 16 m-tiles (4 waves x 4).
__global__ __launch_bounds__(256) void conv2_mfma(const unsigned short* __restrict__ x2,
                                                  const unsigned short* __restrict__ w2p, const float* __restrict__ b2,
                                                  unsigned short* __restrict__ x4, float* __restrict__ ave2) {
    __shared__ unsigned short wl[64 * 296];   // rows padded 288->296 (bank spread)
    __shared__ float red[35];
    const int tid = threadIdx.x;
    {
        const float4* src = (const float4*)w2p;   // 2304 float4
        for (int i = tid; i < 2304; i += 256) {
            int row = i / 36, off = i % 36;
            *(float4*)((char*)wl + row * 592 + off * 16) = src[i];
        }
    }
    if (tid < 35) red[tid] = 0.f;
    __syncthreads();

    const int wave = tid >> 6, lane = tid & 63;
    const int col = lane & 15, quad = lane >> 4;
    const int tile0 = blockIdx.x * 16 + wave * 4;

    const unsigned short* abase[4];
    #pragma unroll
    for (int mi = 0; mi < 4; ++mi) {
        const int m = (tile0 + mi) * 16 + col;
        const int b = m / 35, pos = m % 35;
        const int oh = pos / 7, ow = pos % 7;
        abase[mi] = x2 + ((size_t)b * 165 + oh * 30 + ow * 2) * 32 + quad * 8;
    }
    f32x4 acc[4][4] = {};
    #pragma unroll
    for (int c = 0; c < 9; ++c) {             // k' = c*32 + quad*8 + j ; khw = c
        const int kh = c / 3, kw = c % 3;
        short8 Bf[4];
        #pragma unroll
        for (int nt = 0; nt < 4; ++nt)
            Bf[nt] = *(const short8*)((const char*)wl + ((nt * 16 + col) * 296 + c * 32 + quad * 8) * 2);
        #pragma unroll
        for (int mi = 0; mi < 4; ++mi) {
            short8 af = *(const short8*)(abase[mi] + (kh * 15 + kw) * 32);
            #pragma unroll
            for (int nt = 0; nt < 4; ++nt)
                acc[mi][nt] = MFMA_BF16(af, Bf[nt], acc[mi][nt], 0, 0, 0);
        }
    }
    float bv[4];
    #pragma unroll
    for (int nt = 0; nt < 4; ++nt) bv[nt] = b2[nt * 16 + col];
    #pragma unroll
    for (int mi = 0; mi < 4; ++mi) {
        const int mrow0 = (tile0 + mi) * 16;
        #pragma unroll
        for (int r = 0; r < 4; ++r) {
            const int m = mrow0 + quad * 4 + r;
            const int b = m / 35, pos = m % 35;
            unsigned short* dst = x4 + ((size_t)b * 35 + pos) * 64;
            float s = 0.f;
            #pragma unroll
            for (int nt = 0; nt < 4; ++nt) {
                float v = acc[mi][nt][r] + bv[nt];
                s += v;
                dst[nt * 16 + col] = f2bf(frelu(v));
            }
            s += __shfl_xor(s, 1); s += __shfl_xor(s, 2); s += __shfl_xor(s, 4); s += __shfl_xor(s, 8);
            if (col == 0) atomicAdd(&red[pos], s);
        }
    }
    __syncthreads();
    if (tid < 35) atomicAdd(&ave2[tid], red[tid] * 0.015625f);
}

// ---------------- conv3 (MFMA): x4[B,35,64] * w3p -> x6 bf16 [B,960] (NHWC=(pos,oc)); fused ave3 ----------------
// M = 4096*15 = 61440 = 3840 tiles. grid = (240, 2): y splits oc into halves (LDS < 64 KB).
__global__ __launch_bounds__(256) void conv3_mfma(const unsigned short* __restrict__ x4,
                                                  const unsigned short* __restrict__ w3p, const float* __restrict__ b3,
                                                  unsigned short* __restrict__ x6, float* __restrict__ ave3) {
    __shared__ unsigned short wl[32 * 584];   // rows padded 576->584
    __shared__ float red[15];
    const int tid = threadIdx.x;
    const int oc0 = blockIdx.y * 32;
    {
        const float4* src = (const float4*)(w3p + (size_t)oc0 * 576);  // 32*576*2/16 = 2304 float4
        for (int i = tid; i < 2304; i += 256) {
            int row = i / 72, off = i % 72;
            *(float4*)((char*)wl + row * 1168 + off * 16) = src[i];
        }
    }
    if (tid < 15) red[tid] = 0.f;
    __syncthreads();

    const int wave = tid >> 6, lane = tid & 63;
    const int col = lane & 15, quad = lane >> 4;
    const int tile0 = blockIdx.x * 16 + wave * 4;

    const unsigned short* abase[4];
    #pragma unroll
    for (int mi = 0; mi < 4; ++mi) {
        const int m = (tile0 + mi) * 16 + col;
        const int b = m / 15, pos = m % 15;
        const int oh = pos / 5, ow = pos % 5;
        abase[mi] = x4 + ((size_t)b * 35 + oh * 7 + ow) * 64 + quad * 8;
    }
    f32x4 acc[4][2] = {};
    #pragma unroll
    for (int c = 0; c < 18; ++c) {            // k' = c*32 + quad*8 + j ; khw = c>>1, ic = (c&1)*32 + q*8+j
        const int khw = c >> 1, kh = khw / 3, kw = khw % 3;
        const int icoff = (c & 1) * 32;
        short8 Bf[2];
        #pragma unroll
        for (int nt = 0; nt < 2; ++nt)
            Bf[nt] = *(const short8*)((const char*)wl + ((nt * 16 + col) * 584 + c * 32 + quad * 8) * 2);
        #pragma unroll
        for (int mi = 0; mi < 4; ++mi) {
            short8 af = *(const short8*)(abase[mi] + (kh * 7 + kw) * 64 + icoff);
            #pragma unroll
            for (int nt = 0; nt < 2; ++nt)
                acc[mi][nt] = MFMA_BF16(af, Bf[nt], acc[mi][nt], 0, 0, 0);
        }
    }
    float bv[2];
    #pragma unroll
    for (int nt = 0; nt < 2; ++nt) bv[nt] = b3[oc0 + nt * 16 + col];
    #pragma unroll
    for (int mi = 0; mi < 4; ++mi) {
        const int mrow0 = (tile0 + mi) * 16;
        #pragma unroll
        for (int r = 0; r < 4; ++r) {
            const int m = mrow0 + quad * 4 + r;
            const int b = m / 15, pos = m % 15;
            unsigned short* dst = x6 + (size_t)b * 960 + pos * 64 + oc0;
            float s = 0.f;
            #pragma unroll
            for (int nt = 0; nt < 2; ++nt) {
                float v = acc[mi][nt][r] + bv[nt];
                s += v;
                dst[nt * 16 + col] = f2bf(frelu(v));
            }
            s += __shfl_xor(s, 1); s += __shfl_xor(s, 2); s += __shfl_xor(s, 4); s += __shfl_xor(s, 8);
            if (col == 0) atomicAdd(&red[pos], s);
        }
    }
    __syncthreads();
    if (tid < 15) atomicAdd(&ave3[tid], red[tid] * 0.015625f);
}

// ---------------- fc4+fc5 (MFMA): out[b,2] += relu(x6@w4p^T + b4) @ w5^T ----------------
// grid (32,8): 128 m-rows x 64 oc per block; wave: 2 m-tiles x 4 n-tiles, K=30 chunks.
__global__ __launch_bounds__(256) void fc4_mfma(const unsigned short* __restrict__ x6,
                                                const unsigned short* __restrict__ w4p, const float* __restrict__ b4,
                                                const float* __restrict__ w5, float* __restrict__ out) {
    const int tid = threadIdx.x;
    const int wave = tid >> 6, lane = tid & 63;
    const int col = lane & 15, quad = lane >> 4;
    const int m0 = blockIdx.x * 128 + wave * 32;
    const int n0 = blockIdx.y * 64;

    const unsigned short* arow0 = x6 + (size_t)(m0 + col) * 960 + quad * 8;
    const unsigned short* arow1 = arow0 + 16 * 960;
    f32x4 acc[2][4] = {};
    for (int c = 0; c < 30; ++c) {
        short8 Bf[4];
        #pragma unroll
        for (int nt = 0; nt < 4; ++nt)
            Bf[nt] = *(const short8*)(w4p + (size_t)(n0 + nt * 16 + col) * 960 + c * 32 + quad * 8);
        short8 a0 = *(const short8*)(arow0 + c * 32);
        short8 a1 = *(const short8*)(arow1 + c * 32);
        #pragma unroll
        for (int nt = 0; nt < 4; ++nt) {
            acc[0][nt] = MFMA_BF16(a0, Bf[nt], acc[0][nt], 0, 0, 0);
            acc[1][nt] = MFMA_BF16(a1, Bf[nt], acc[1][nt], 0, 0, 0);
        }
    }
    float bv[4], w50[4], w51[4];
    #pragma unroll
    for (int nt = 0; nt < 4; ++nt) {
        const int oc = n0 + nt * 16 + col;
        bv[nt] = b4[oc]; w50[nt] = w5[oc]; w51[nt] = w5[512 + oc];
    }
    #pragma unroll
    for (int mi = 0; mi < 2; ++mi) {
        #pragma unroll
        for (int r = 0; r < 4; ++r) {
            float l0 = 0.f, l1 = 0.f;
            #pragma unroll
            for (int nt = 0; nt < 4; ++nt) {
                float hh = frelu(acc[mi][nt][r] + bv[nt]);
                l0 += hh * w50[nt];
                l1 += hh * w51[nt];
            }
            l0 += __shfl_xor(l0, 1); l0 += __shfl_xor(l0, 2); l0 += __shfl_xor(l0, 4); l0 += __shfl_xor(l0, 8);
            l1 += __shfl_xor(l1, 1); l1 += __shfl_xor(l1, 2); l1 += __shfl_xor(l1, 4); l1 += __shfl_xor(l1, 8);
            if (col == 0) {
                const int gm = m0 + mi * 16 + quad * 4 + r;
                atomicAdd(&out[gm * 2 + 0], l0);
                atomicAdd(&out[gm * 2 + 1], l1);
            }
        }
    }
}

extern "C" void kernel_launch(void* const* d_in, const int* in_sizes, int n_in,
                              void* d_out, int out_size, void* d_ws, size_t ws_size,
                              hipStream_t stream) {
    const float* x  = (const float*)d_in[0];
    const float* w1 = (const float*)d_in[1];
    const float* b1 = (const float*)d_in[2];
    const float* w2 = (const float*)d_in[3];
    const float* b2 = (const float*)d_in[4];
    const float* w3 = (const float*)d_in[5];
    const float* b3 = (const float*)d_in[6];
    const float* w4 = (const float*)d_in[7];
    const float* b4 = (const float*)d_in[8];
    const float* w5 = (const float*)d_in[9];
    const float* b5 = (const float*)d_in[10];
    float* out = (float*)d_out;

    unsigned short* ws = (unsigned short*)d_ws;
    unsigned short* x2  = ws;                      // 21,626,880 ushort
    unsigned short* x4  = ws + 21626880;           //  9,175,040
    unsigned short* x6  = ws + 30801920;           //  3,932,160
    unsigned short* w2p = ws + 34734080;           //     18,432
    unsigned short* w3p = ws + 34752512;           //     36,864
    unsigned short* w4p = ws + 34789376;           //    491,520
    float* red1 = (float*)((char*)d_ws + 70561792); // 176*4096 floats

    float* ave1 = out + 8192;
    float* ave2 = out + 8192 + 165;
    float* ave3 = out + 8192 + 200;

    prep_kernel<<<2169, 256, 0, stream>>>(w2, w3, w4, b5, w2p, w3p, w4p, out);
    conv1_mfma<<<BATCH, 256, 0, stream>>>(x, w1, b1, x2, red1);
    reduce1_kernel<<<165, 256, 0, stream>>>(red1, ave1);
    conv2_mfma<<<560, 256, 0, stream>>>(x2, w2p, b2, x4, ave2);
    conv3_mfma<<<dim3(240, 2), 256, 0, stream>>>(x4, w3p, b3, x6, ave3);
    fc4_mfma<<<dim3(32, 8), 256, 0, stream>>>(x6, w4p, b4, w5, out);
}